// Round 3
// baseline (388.140 us; speedup 1.0000x reference)
//
#include <hip/hip_runtime.h>
#include <hip/hip_bf16.h>

// Problem constants
#define BB 8192
#define NN 8192
#define DD 256
#define GAMMA_INV_2SQ 0.0078125f   // 1/(2*8^2) = 1/128
#define EPS_C 0.001f

typedef __attribute__((ext_vector_type(8))) short v8s;   // 8 bf16 (4 VGPRs)
typedef __attribute__((ext_vector_type(4))) float v4f;   // MFMA acc

__device__ inline unsigned short f2bf(float f) {
    union { float f; unsigned int u; } v; v.f = f;
    unsigned int r = v.u + 0x7FFFu + ((v.u >> 16) & 1u);  // RNE
    return (unsigned short)(r >> 16);
}

// ---------------- zero d_out (M accumulator) without hipMemsetAsync
__global__ __launch_bounds__(256) void zero_k(float4* __restrict__ p) {
    p[(size_t)blockIdx.x * 256 + threadIdx.x] = make_float4(0.f, 0.f, 0.f, 0.f);
}

// ---------------- prep: ref -> ref_bf16 [N][D], refT [D][N], ref2T [D][N], rsq [N]
__global__ __launch_bounds__(256) void prep_ref(const float* __restrict__ ref,
                                                unsigned short* __restrict__ refA,
                                                unsigned short* __restrict__ refT,
                                                unsigned short* __restrict__ ref2T,
                                                float* __restrict__ rsq) {
    __shared__ float tile[32][257];
    __shared__ float rs[32];
    const int tid = threadIdx.x;
    const int n0 = blockIdx.x * 32;
    if (tid < 32) rs[tid] = 0.f;
    __syncthreads();
    const int r = tid >> 3, p = tid & 7;
    float partial = 0.f;
#pragma unroll
    for (int j = 0; j < 8; ++j) {
        const int c = p * 32 + j * 4;
        const float4 v = *(const float4*)(ref + (size_t)(n0 + r) * DD + c);
        partial += v.x * v.x + v.y * v.y + v.z * v.z + v.w * v.w;
        uint2 pk;
        pk.x = (unsigned int)f2bf(v.x) | ((unsigned int)f2bf(v.y) << 16);
        pk.y = (unsigned int)f2bf(v.z) | ((unsigned int)f2bf(v.w) << 16);
        *(uint2*)(refA + (size_t)(n0 + r) * DD + c) = pk;
        tile[r][c + 0] = v.x; tile[r][c + 1] = v.y;
        tile[r][c + 2] = v.z; tile[r][c + 3] = v.w;
    }
    atomicAdd(&rs[r], partial);
    __syncthreads();
    if (tid < 32) rsq[n0 + tid] = rs[tid];
    // transpose: this thread owns column d = tid
    unsigned int r1[16], r2[16];
#pragma unroll
    for (int n = 0; n < 16; ++n) {
        const float a = tile[2 * n][tid], b = tile[2 * n + 1][tid];
        r1[n] = (unsigned int)f2bf(a) | ((unsigned int)f2bf(b) << 16);
        r2[n] = (unsigned int)f2bf(a * a) | ((unsigned int)f2bf(b * b) << 16);
    }
#pragma unroll
    for (int k = 0; k < 4; ++k) {
        uint4 o1, o2;
        o1.x = r1[4 * k]; o1.y = r1[4 * k + 1]; o1.z = r1[4 * k + 2]; o1.w = r1[4 * k + 3];
        o2.x = r2[4 * k]; o2.y = r2[4 * k + 1]; o2.z = r2[4 * k + 2]; o2.w = r2[4 * k + 3];
        *(uint4*)(refT  + (size_t)tid * NN + n0 + k * 8) = o1;
        *(uint4*)(ref2T + (size_t)tid * NN + n0 + k * 8) = o2;
    }
}

// ---------------- prep: x -> x_bf16 [B][D], xsq [B]
__global__ __launch_bounds__(256) void prep_x(const float* __restrict__ x,
                                              unsigned short* __restrict__ xbf,
                                              float* __restrict__ xsq) {
    __shared__ float rs[32];
    const int tid = threadIdx.x;
    const int b0 = blockIdx.x * 32;
    if (tid < 32) rs[tid] = 0.f;
    __syncthreads();
    const int r = tid >> 3, p = tid & 7;
    float partial = 0.f;
#pragma unroll
    for (int j = 0; j < 8; ++j) {
        const int c = p * 32 + j * 4;
        const float4 v = *(const float4*)(x + (size_t)(b0 + r) * DD + c);
        partial += v.x * v.x + v.y * v.y + v.z * v.z + v.w * v.w;
        uint2 pk;
        pk.x = (unsigned int)f2bf(v.x) | ((unsigned int)f2bf(v.y) << 16);
        pk.y = (unsigned int)f2bf(v.z) | ((unsigned int)f2bf(v.w) << 16);
        *(uint2*)(xbf + (size_t)(b0 + r) * DD + c) = pk;
    }
    atomicAdd(&rs[r], partial);
    __syncthreads();
    if (tid < 32) xsq[b0 + tid] = rs[tid];
}

// ---------------- main fused kernel (fast path, needs ~16.85 MB workspace)
// grid = 128 b-tiles (BT=64) x 4 n-splits = 512 blocks, 512 threads (8 waves)
#define SA_OFF   0               // ref tile bf16 [32 rows][264 els] stride 528B -> 16896
#define ST_OFF   16896           // refT tile bf16 [256 d][40 els] stride 80B   -> 20480
#define ST2_OFF  37376           // ref2T tile                                   -> 20480
#define SW_OFF   57856           // w bf16 [64 b][40 els] stride 80B             -> 5120
#define SRSQ_OFF 62976           // float[32]
#define SWS_OFF  63104           // float[8][16]
#define SMEM_SZ  63616

__global__ __launch_bounds__(512, 4) void hland_main(
        const unsigned short* __restrict__ refA,
        const unsigned short* __restrict__ refT,
        const unsigned short* __restrict__ ref2T,
        const float* __restrict__ rsq,
        const float* __restrict__ xsq,
        const unsigned short* __restrict__ xbf,
        const float* __restrict__ x_t,
        float* __restrict__ M) {
    __shared__ __align__(16) char smem[SMEM_SZ];

    const int tid = threadIdx.x;
    const int wave = tid >> 6, lane = tid & 63;
    const int quad = lane >> 4, l16 = lane & 15;
    const int btile = blockIdx.x >> 2;          // 0..127
    const int q = blockIdx.x & 3;               // n-quarter
    const int b0 = btile * 64;
    const int n_begin = q * (NN / 4);           // q*2048
    const int nt = wave & 1;                    // step1: n-subtile (0..1)
    const int btA = wave >> 1;                  // step1: b-subtile (0..3)
    const int dq = wave;                        // step3: 32-wide d slice

    const float xsq_lane = xsq[b0 + btA * 16 + l16];
    float wsum_acc = 0.f;
    v4f acc2[4][2], acc1[4][2];
#pragma unroll
    for (int i = 0; i < 4; ++i)
#pragma unroll
        for (int j = 0; j < 2; ++j) { acc2[i][j] = (v4f){0,0,0,0}; acc1[i][j] = (v4f){0,0,0,0}; }

    for (int it = 0; it < (NN / 4) / 32; ++it) {
        const int n0 = n_begin + it * 32;
        // ---- Phase A: stage tiles (3072 x 16B chunks over 512 threads x 2)
#pragma unroll
        for (int s = 0; s < 2; ++s) {
            const int idx = tid + s * 512;
            {   // sA: row-major ref tile
                const int r = idx >> 5, cc = idx & 31;
                const uint4 v = *(const uint4*)(refA + (size_t)(n0 + r) * DD + cc * 8);
                *(uint4*)(smem + SA_OFF + r * 528 + cc * 16) = v;
            }
            {   // sT / sT2: transposed tiles
                const int d = idx >> 2, p = idx & 3;
                const uint4 t1 = *(const uint4*)(refT + (size_t)d * NN + n0 + p * 8);
                *(uint4*)(smem + ST_OFF + d * 80 + p * 16) = t1;
                const uint4 t2 = *(const uint4*)(ref2T + (size_t)d * NN + n0 + p * 8);
                *(uint4*)(smem + ST2_OFF + d * 80 + p * 16) = t2;
            }
        }
        if (tid < 32) ((float*)(smem + SRSQ_OFF))[tid] = rsq[n0 + tid];
        __syncthreads();

        // ---- Phase B: S^T[n][b] = sum_d ref[n][d]*x[b][d]  (one 16x16 tile per wave)
        v4f S = (v4f){0,0,0,0};
#pragma unroll
        for (int kc = 0; kc < 8; ++kc) {
            const v8s a = *(const v8s*)(smem + SA_OFF + (nt * 16 + l16) * 528 + kc * 64 + quad * 16);
            const v8s b = *(const v8s*)(xbf + (size_t)(b0 + btA * 16 + l16) * DD + kc * 32 + quad * 8);
            S = __builtin_amdgcn_mfma_f32_16x16x32_bf16(a, b, S, 0, 0, 0);
        }

        // ---- Phase C: w = exp(-dist/128), pack to LDS [b][n], accumulate wsum
        {
            const float* rsqs = (const float*)(smem + SRSQ_OFF);
            float wv[4];
#pragma unroll
            for (int r = 0; r < 4; ++r) {
                const float dist = xsq_lane + rsqs[nt * 16 + quad * 4 + r] - 2.f * S[r];
                wv[r] = __expf(dist * (-GAMMA_INV_2SQ));
            }
            wsum_acc += wv[0] + wv[1] + wv[2] + wv[3];
            uint2 pk;
            pk.x = (unsigned int)f2bf(wv[0]) | ((unsigned int)f2bf(wv[1]) << 16);
            pk.y = (unsigned int)f2bf(wv[2]) | ((unsigned int)f2bf(wv[3]) << 16);
            *(uint2*)(smem + SW_OFF + (btA * 16 + l16) * 80 + (nt * 16 + quad * 4) * 2) = pk;
        }
        __syncthreads();

        // ---- Phase D: acc2 += w @ ref2, acc1 += w @ ref   (16 MFMAs / wave)
        {
            v8s wf[4];
#pragma unroll
            for (int bt = 0; bt < 4; ++bt)
                wf[bt] = *(const v8s*)(smem + SW_OFF + (bt * 16 + l16) * 80 + quad * 16);
#pragma unroll
            for (int dt = 0; dt < 2; ++dt) {
                const int d = dq * 32 + dt * 16 + l16;
                const v8s bT  = *(const v8s*)(smem + ST_OFF  + d * 80 + quad * 16);
                const v8s bT2 = *(const v8s*)(smem + ST2_OFF + d * 80 + quad * 16);
#pragma unroll
                for (int bt = 0; bt < 4; ++bt) {
                    acc2[bt][dt] = __builtin_amdgcn_mfma_f32_16x16x32_bf16(wf[bt], bT2, acc2[bt][dt], 0, 0, 0);
                    acc1[bt][dt] = __builtin_amdgcn_mfma_f32_16x16x32_bf16(wf[bt], bT,  acc1[bt][dt], 0, 0, 0);
                }
            }
        }
        __syncthreads();
    }

    // ---- epilogue: wsum reduce, combine M partial, atomicAdd to M buffer
    float v = wsum_acc;
    v += __shfl_xor(v, 16, 64);
    v += __shfl_xor(v, 32, 64);
    float* swsum = (float*)(smem + SWS_OFF);
    if (lane < 16) swsum[wave * 16 + lane] = v;   // partial wsum for b=btA*16+lane over nt half
    __syncthreads();

#pragma unroll
    for (int bt = 0; bt < 4; ++bt) {
#pragma unroll
        for (int dt = 0; dt < 2; ++dt) {
            const int d = dq * 32 + dt * 16 + l16;
#pragma unroll
            for (int r = 0; r < 4; ++r) {
                const int bl = bt * 16 + quad * 4 + r;
                const int b = b0 + bl;
                const float wsb = swsum[(bt * 2) * 16 + (quad * 4 + r)]
                                + swsum[(bt * 2 + 1) * 16 + (quad * 4 + r)];
                const float xv = x_t[(size_t)b * DD + d];
                const float m = acc2[bt][dt][r] - 2.f * xv * acc1[bt][dt][r] + xv * xv * wsb;
                atomicAdd(&M[(size_t)b * DD + d], m);
            }
        }
    }
}

// ---------------- fallback: fp32, ZERO workspace. 8 b-rows per block.
// grid = 1024 blocks x 256 threads. Writes full M directly (no atomics).
__global__ __launch_bounds__(256) void hland_fb(const float* __restrict__ x_t,
                                                const float* __restrict__ ref,
                                                float* __restrict__ M) {
    __shared__ float xs[8][257];
    __shared__ float rt[32][257];
    __shared__ float Sv[8][32];
    __shared__ float wv[8][32];
    __shared__ float rsq_s[32];
    __shared__ float xsq_s[8];
    const int t = threadIdx.x;
    const int b0 = blockIdx.x * 8;

    if (t < 8) xsq_s[t] = 0.f;
    __syncthreads();
    {   // load x rows + xsq
        const int r = t >> 5, c = (t & 31) * 8;
        const float4 a = *(const float4*)(x_t + (size_t)(b0 + r) * DD + c);
        const float4 b = *(const float4*)(x_t + (size_t)(b0 + r) * DD + c + 4);
        xs[r][c + 0] = a.x; xs[r][c + 1] = a.y; xs[r][c + 2] = a.z; xs[r][c + 3] = a.w;
        xs[r][c + 4] = b.x; xs[r][c + 5] = b.y; xs[r][c + 6] = b.z; xs[r][c + 7] = b.w;
        const float p = a.x * a.x + a.y * a.y + a.z * a.z + a.w * a.w
                      + b.x * b.x + b.y * b.y + b.z * b.z + b.w * b.w;
        atomicAdd(&xsq_s[r], p);
    }
    __syncthreads();

    float acc2[8], acc1[8], wsum[8];
#pragma unroll
    for (int b = 0; b < 8; ++b) { acc2[b] = 0.f; acc1[b] = 0.f; wsum[b] = 0.f; }

    const int sr = t >> 3, sg = t & 7;   // staging/cross roles
    for (int tile = 0; tile < NN / 32; ++tile) {
        const int n0 = tile * 32;
        // zero per-tile reduction buffers (disjoint from rt/wv still being read)
        Sv[t >> 5][t & 31] = 0.f;
        if (t < 32) rsq_s[t] = 0.f;
        __syncthreads();
        // stage ref rows + rsq partials
        {
            float p = 0.f;
#pragma unroll
            for (int j = 0; j < 8; ++j) {
                const int c = sg * 32 + j * 4;
                const float4 v = *(const float4*)(ref + (size_t)(n0 + sr) * DD + c);
                rt[sr][c + 0] = v.x; rt[sr][c + 1] = v.y; rt[sr][c + 2] = v.z; rt[sr][c + 3] = v.w;
                p += v.x * v.x + v.y * v.y + v.z * v.z + v.w * v.w;
            }
            atomicAdd(&rsq_s[sr], p);
        }
        __syncthreads();
        // cross terms: thread (n=sr, g=sg) sums its 32-d chunk for all 8 b
        {
            float part[8];
#pragma unroll
            for (int b = 0; b < 8; ++b) part[b] = 0.f;
            for (int jj = 0; jj < 32; ++jj) {
                const int c = sg * 32 + ((jj + sg * 4) & 31);   // bank-rotated
                const float rv = rt[sr][c];
#pragma unroll
                for (int b = 0; b < 8; ++b) part[b] += xs[b][c] * rv;
            }
#pragma unroll
            for (int b = 0; b < 8; ++b) atomicAdd(&Sv[b][sr], part[b]);
        }
        __syncthreads();
        // weights
        {
            const int b = t >> 5, n = t & 31;
            const float dist = xsq_s[b] + rsq_s[n] - 2.f * Sv[b][n];
            wv[b][n] = __expf(dist * (-GAMMA_INV_2SQ));
        }
        __syncthreads();
        // accumulate: thread owns column d = t
        for (int n = 0; n < 32; ++n) {
            const float rv = rt[n][t];
            const float rv2 = rv * rv;
#pragma unroll
            for (int b = 0; b < 8; ++b) {
                const float w = wv[b][n];
                acc1[b] += w * rv;
                acc2[b] += w * rv2;
                wsum[b] += w;
            }
        }
        __syncthreads();
    }
#pragma unroll
    for (int b = 0; b < 8; ++b) {
        const float xv = xs[b][t];
        M[(size_t)(b0 + b) * DD + t] = acc2[b] - 2.f * xv * acc1[b] + xv * xv * wsum[b];
    }
}

// ---------------- finish: out = 1/(W*M + eps), in place on d_out
__global__ __launch_bounds__(256) void finish_k(float* __restrict__ M,
                                                const float* __restrict__ W) {
    const int i = blockIdx.x * blockDim.x + threadIdx.x;
    const float W0 = W[0];
    float4 m = ((const float4*)M)[i];
    float4 o;
    o.x = 1.f / (W0 * m.x + EPS_C);
    o.y = 1.f / (W0 * m.y + EPS_C);
    o.z = 1.f / (W0 * m.z + EPS_C);
    o.w = 1.f / (W0 * m.w + EPS_C);
    ((float4*)M)[i] = o;
}

extern "C" void kernel_launch(void* const* d_in, const int* in_sizes, int n_in,
                              void* d_out, int out_size, void* d_ws, size_t ws_size,
                              hipStream_t stream) {
    const float* x_t = (const float*)d_in[0];
    const float* ref = (const float*)d_in[1];
    const float* W   = (const float*)d_in[2];
    float* out = (float*)d_out;

    // workspace carve (bytes): refA 4MB | refT 4MB | ref2T 4MB | xbf 4MB | rsq 32KB | xsq 32KB
    const size_t WS_NEED = (size_t)16 * 1024 * 1024 + 65536;
    if (ws_size >= WS_NEED) {
        char* ws = (char*)d_ws;
        unsigned short* refA  = (unsigned short*)(ws);
        unsigned short* refT  = (unsigned short*)(ws + (size_t)4 * 1024 * 1024);
        unsigned short* ref2T = (unsigned short*)(ws + (size_t)8 * 1024 * 1024);
        unsigned short* xbf   = (unsigned short*)(ws + (size_t)12 * 1024 * 1024);
        float* rsq = (float*)(ws + (size_t)16 * 1024 * 1024);
        float* xsq = (float*)(ws + (size_t)16 * 1024 * 1024 + 32768);

        zero_k<<<(BB * DD / 4) / 256, 256, 0, stream>>>((float4*)out);
        prep_ref<<<NN / 32, 256, 0, stream>>>(ref, refA, refT, ref2T, rsq);
        prep_x<<<BB / 32, 256, 0, stream>>>(x_t, xbf, xsq);
        hland_main<<<(BB / 64) * 4, 512, 0, stream>>>(refA, refT, ref2T, rsq, xsq, xbf, x_t, out);
    } else {
        // no-workspace fp32 fallback
        hland_fb<<<BB / 8, 256, 0, stream>>>(x_t, ref, out);
    }
    finish_k<<<(BB * DD / 4) / 256, 256, 0, stream>>>(out, W);
}

// Round 4
// 184.317 us; speedup vs baseline: 2.1058x; 2.1058x over previous
//
#include <hip/hip_runtime.h>
#include <hip/hip_bf16.h>

// Problem constants
#define BB 8192
#define NN 8192
#define DD 256
#define GAMMA_INV_2SQ 0.0078125f   // 1/(2*8^2) = 1/128
#define EPS_C 0.001f

typedef __attribute__((ext_vector_type(4))) float v4f;   // MFMA acc

// ---- fp8 (OCP e4m3) pack: 4 floats -> u32 (byte0=a .. byte3=d), RNE in HW
__device__ __forceinline__ unsigned f2fp8pk4(float a, float b, float c, float d) {
    int v = 0;
    v = __builtin_amdgcn_cvt_pk_fp8_f32(a, b, v, false);  // low word
    v = __builtin_amdgcn_cvt_pk_fp8_f32(c, d, v, true);   // high word
    return (unsigned)v;
}

// ---- async global->LDS, 16B per lane (lds base wave-uniform)
typedef const __attribute__((address_space(1))) void* gas_t;
typedef __attribute__((address_space(3))) void* las_t;
__device__ __forceinline__ void ld16(const void* g, void* l) {
    __builtin_amdgcn_global_load_lds((gas_t)g, (las_t)l, 16, 0, 0);
}

// ---------------- zero d_out (M accumulator)
__global__ __launch_bounds__(256) void zero_k(float4* __restrict__ p) {
    p[(size_t)blockIdx.x * 256 + threadIdx.x] = make_float4(0.f, 0.f, 0.f, 0.f);
}

// ---------------- prep: ref -> swizzled fp8 tile images + rsq
// sAg tile (8KB): byte[r*256 + cp*8 + j] = fp8(ref[n0+r][c*8+j]), cp=(c&16)|((c^(r&15))&15)
// sTg tile (8KB): byte[d*32 + cp*8 + j] = fp8(ref[n0+c*8+j][d]),  cp=c^((d>>2)&3)
// sT2g: same with fp8(ref^2)
__global__ __launch_bounds__(256) void prep_ref(const float* __restrict__ ref,
                                                unsigned char* __restrict__ sAg,
                                                unsigned char* __restrict__ sTg,
                                                unsigned char* __restrict__ sT2g,
                                                float* __restrict__ rsq) {
    __shared__ float tile[32][257];
    __shared__ float rs[32];
    const int tid = threadIdx.x;
    const int n0 = blockIdx.x * 32;
    if (tid < 32) rs[tid] = 0.f;
    __syncthreads();
    const int r = tid >> 3, p8 = tid & 7;
    float partial = 0.f;
#pragma unroll
    for (int j = 0; j < 8; ++j) {
        const int c = p8 * 32 + j * 4;
        const float4 v = *(const float4*)(ref + (size_t)(n0 + r) * DD + c);
        partial += v.x * v.x + v.y * v.y + v.z * v.z + v.w * v.w;
        tile[r][c + 0] = v.x; tile[r][c + 1] = v.y;
        tile[r][c + 2] = v.z; tile[r][c + 3] = v.w;
    }
    atomicAdd(&rs[r], partial);
    __syncthreads();
    if (tid < 32) rsq[n0 + tid] = rs[tid];
    // sAg image: thread (r, p8) owns chunks c = p8*4 .. p8*4+3 of row r
    {
        unsigned char* dstA = sAg + (size_t)blockIdx.x * 8192 + r * 256;
#pragma unroll
        for (int c4 = 0; c4 < 4; ++c4) {
            const int c = p8 * 4 + c4;
            const float* s = &tile[r][c * 8];
            const unsigned lo = f2fp8pk4(s[0], s[1], s[2], s[3]);
            const unsigned hi = f2fp8pk4(s[4], s[5], s[6], s[7]);
            const int cp = (c & 16) | ((c ^ (r & 15)) & 15);
            *(uint2*)(dstA + cp * 8) = make_uint2(lo, hi);
        }
    }
    // sTg / sT2g: thread owns column d = tid
    {
        const int d = tid;
        uint2 ch1[4], ch2[4];
#pragma unroll
        for (int c = 0; c < 4; ++c) {
            float v[8], v2[8];
#pragma unroll
            for (int j = 0; j < 8; ++j) { v[j] = tile[c * 8 + j][d]; v2[j] = v[j] * v[j]; }
            const int cp = c ^ ((d >> 2) & 3);
            ch1[cp] = make_uint2(f2fp8pk4(v[0], v[1], v[2], v[3]), f2fp8pk4(v[4], v[5], v[6], v[7]));
            ch2[cp] = make_uint2(f2fp8pk4(v2[0], v2[1], v2[2], v2[3]), f2fp8pk4(v2[4], v2[5], v2[6], v2[7]));
        }
        unsigned char* dT  = sTg  + (size_t)blockIdx.x * 8192 + d * 32;
        unsigned char* dT2 = sT2g + (size_t)blockIdx.x * 8192 + d * 32;
        *(uint4*)(dT)       = make_uint4(ch1[0].x, ch1[0].y, ch1[1].x, ch1[1].y);
        *(uint4*)(dT + 16)  = make_uint4(ch1[2].x, ch1[2].y, ch1[3].x, ch1[3].y);
        *(uint4*)(dT2)      = make_uint4(ch2[0].x, ch2[0].y, ch2[1].x, ch2[1].y);
        *(uint4*)(dT2 + 16) = make_uint4(ch2[2].x, ch2[2].y, ch2[3].x, ch2[3].y);
    }
}

// ---------------- prep: x -> fp8 rows + xsq
__global__ __launch_bounds__(256) void prep_x(const float* __restrict__ x,
                                              unsigned char* __restrict__ xbf8,
                                              float* __restrict__ xsq) {
    __shared__ float rs[32];
    const int tid = threadIdx.x;
    const int b0 = blockIdx.x * 32;
    if (tid < 32) rs[tid] = 0.f;
    __syncthreads();
    const int r = tid >> 3, p8 = tid & 7;
    float partial = 0.f;
    unsigned pk[8];
#pragma unroll
    for (int j = 0; j < 8; ++j) {
        const int c = p8 * 32 + j * 4;
        const float4 v = *(const float4*)(x + (size_t)(b0 + r) * DD + c);
        partial += v.x * v.x + v.y * v.y + v.z * v.z + v.w * v.w;
        pk[j] = f2fp8pk4(v.x, v.y, v.z, v.w);
    }
    atomicAdd(&rs[r], partial);
    unsigned char* dst = xbf8 + (size_t)(b0 + r) * DD + p8 * 32;
    *(uint4*)(dst)      = make_uint4(pk[0], pk[1], pk[2], pk[3]);
    *(uint4*)(dst + 16) = make_uint4(pk[4], pk[5], pk[6], pk[7]);
    __syncthreads();
    if (tid < 32) xsq[b0 + tid] = rs[tid];
}

// ---------------- main fused kernel: fp8 MFMA, 1 barrier/iter, async staging
// grid = 128 btiles x 4 n-quarters = 512 blocks, 512 threads (8 waves)
// LDS (bytes): sA 2x8192 | sT 3x8192 | sT2 3x8192 | sW 2x2048 | wsum 512
#define SA_OFF   0
#define ST_OFF   16384
#define ST2_OFF  40960
#define SW_OFF   65536
#define SWS_OFF  69632
#define SMEM_SZ  70144

__global__ __launch_bounds__(512, 4) void hland_main(
        const unsigned char* __restrict__ sAg,
        const unsigned char* __restrict__ sTg,
        const unsigned char* __restrict__ sT2g,
        const float* __restrict__ rsq,
        const float* __restrict__ xsq,
        const unsigned char* __restrict__ xbf8,
        const float* __restrict__ x_t,
        float* __restrict__ M) {
    __shared__ __align__(16) char smem[SMEM_SZ];

    const int tid = threadIdx.x;
    const int wave = tid >> 6, lane = tid & 63;
    const int quad = lane >> 4, l16 = lane & 15;
    const int btile = blockIdx.x >> 2;
    const int q = blockIdx.x & 3;
    const int b0 = btile * 64;
    const int tn0 = q * 64;                 // absolute 32-n tile index base
    const int nt = wave & 1, btA = wave >> 1, dq = wave;

    const float xsq_lane = xsq[b0 + btA * 16 + l16];
    float wsum_acc = 0.f;
    v4f acc2[4][2], acc1[4][2];
#pragma unroll
    for (int i = 0; i < 4; ++i)
#pragma unroll
        for (int j = 0; j < 2; ++j) { acc2[i][j] = (v4f){0,0,0,0}; acc1[i][j] = (v4f){0,0,0,0}; }

    const int stage_goff = wave * 1024 + lane * 16;   // per-lane global offset
    const int stage_loff = wave * 1024;               // wave-uniform LDS offset

    // prologue: stage tile 0 into slot 0
    {
        const size_t g = (size_t)tn0 * 8192 + stage_goff;
        ld16(sAg + g,  smem + SA_OFF  + stage_loff);
        ld16(sTg + g,  smem + ST_OFF  + stage_loff);
        ld16(sT2g + g, smem + ST2_OFF + stage_loff);
    }
    __syncthreads();

    int sp = 0, tp = 0;
    for (int it = 0; it < 64; ++it) {
        const int spn = sp ^ 1;
        const int tpn = (tp == 2) ? 0 : tp + 1;
        const int tpd = (tp == 0) ? 2 : tp - 1;   // (it-1)%3

        // ---- stage tile it+1 (async; drained by this iter's barrier)
        if (it < 63) {
            const size_t g = (size_t)(tn0 + it + 1) * 8192 + stage_goff;
            ld16(sAg + g,  smem + SA_OFF  + spn * 8192 + stage_loff);
            ld16(sTg + g,  smem + ST_OFF  + tpn * 8192 + stage_loff);
            ld16(sT2g + g, smem + ST2_OFF + tpn * 8192 + stage_loff);
        }

        // ---- Phase B(it): S^T[n][b], A = ref rows (sA[sp]), B = x rows (global fp8)
        v4f S = (v4f){0,0,0,0};
        {
            const char* saB = smem + SA_OFF + sp * 8192 + (nt * 16 + l16) * 256;
            const unsigned char* xb = xbf8 + (size_t)(b0 + btA * 16 + l16) * 256 + quad * 8;
            long bfr[8];
#pragma unroll
            for (int kc = 0; kc < 8; ++kc) bfr[kc] = *(const long*)(xb + kc * 32);
#pragma unroll
            for (int kc = 0; kc < 8; ++kc) {
                const int c = kc * 4 + quad;
                const int cp = (c & 16) | ((c ^ l16) & 15);   // r&15 == l16
                const long a = *(const long*)(saB + cp * 8);
                S = __builtin_amdgcn_mfma_f32_16x16x32_fp8_fp8(a, bfr[kc], S, 0, 0, 0);
            }
        }

        // ---- Phase C(it): w = exp(-dist/128); write 64*w as fp8 to sW[sp]
        {
            float w4[4];
            const int tn = tn0 + it;
#pragma unroll
            for (int r = 0; r < 4; ++r) {
                const int n = nt * 16 + quad * 4 + r;
                const float dist = xsq_lane + rsq[tn * 32 + n] - 2.f * S[r];
                w4[r] = __expf(dist * (-GAMMA_INV_2SQ));
            }
            wsum_acc += w4[0] + w4[1] + w4[2] + w4[3];
            const unsigned pk = f2fp8pk4(w4[0] * 64.f, w4[1] * 64.f, w4[2] * 64.f, w4[3] * 64.f);
            const int bl = btA * 16 + l16;
            const int c8 = nt * 2 + (quad >> 1);
            *(unsigned*)(smem + SW_OFF + sp * 2048 + bl * 32
                         + (c8 ^ ((bl >> 2) & 3)) * 8 + (quad & 1) * 4) = pk;
        }

        // ---- Phase D(it-1): acc += w @ ref2 / w @ ref  (16 fp8 MFMAs/wave)
        if (it > 0) {
            const char* swb  = smem + SW_OFF  + spn * 8192 / 4;   // spn*2048
            const char* stb  = smem + ST_OFF  + tpd * 8192;
            const char* st2b = smem + ST2_OFF + tpd * 8192;
            long wf[4];
#pragma unroll
            for (int bt = 0; bt < 4; ++bt) {
                const int bl = bt * 16 + l16;
                wf[bt] = *(const long*)(swb + bl * 32 + (quad ^ ((bl >> 2) & 3)) * 8);
            }
#pragma unroll
            for (int dt = 0; dt < 2; ++dt) {
                const int d = dq * 32 + dt * 16 + l16;
                const int co = (quad ^ ((d >> 2) & 3)) * 8;
                const long bT  = *(const long*)(stb  + d * 32 + co);
                const long bT2 = *(const long*)(st2b + d * 32 + co);
#pragma unroll
                for (int bt = 0; bt < 4; ++bt) {
                    acc2[bt][dt] = __builtin_amdgcn_mfma_f32_16x16x32_fp8_fp8(wf[bt], bT2, acc2[bt][dt], 0, 0, 0);
                    acc1[bt][dt] = __builtin_amdgcn_mfma_f32_16x16x32_fp8_fp8(wf[bt], bT,  acc1[bt][dt], 0, 0, 0);
                }
            }
        }
        __syncthreads();
        sp = spn; tp = tpn;
    }

    // ---- final Phase D(63): slots (63)%3 = (tp+2)%3, sW slot = sp^1
    {
        const int tpd = (tp == 0) ? 2 : tp - 1;
        const int wsl = sp ^ 1;
        const char* swb  = smem + SW_OFF  + wsl * 2048;
        const char* stb  = smem + ST_OFF  + tpd * 8192;
        const char* st2b = smem + ST2_OFF + tpd * 8192;
        long wf[4];
#pragma unroll
        for (int bt = 0; bt < 4; ++bt) {
            const int bl = bt * 16 + l16;
            wf[bt] = *(const long*)(swb + bl * 32 + (quad ^ ((bl >> 2) & 3)) * 8);
        }
#pragma unroll
        for (int dt = 0; dt < 2; ++dt) {
            const int d = dq * 32 + dt * 16 + l16;
            const int co = (quad ^ ((d >> 2) & 3)) * 8;
            const long bT  = *(const long*)(stb  + d * 32 + co);
            const long bT2 = *(const long*)(st2b + d * 32 + co);
#pragma unroll
            for (int bt = 0; bt < 4; ++bt) {
                acc2[bt][dt] = __builtin_amdgcn_mfma_f32_16x16x32_fp8_fp8(wf[bt], bT2, acc2[bt][dt], 0, 0, 0);
                acc1[bt][dt] = __builtin_amdgcn_mfma_f32_16x16x32_fp8_fp8(wf[bt], bT,  acc1[bt][dt], 0, 0, 0);
            }
        }
    }

    // ---- epilogue: wsum reduce, combine M partial (scale fp8-w by 1/64), atomicAdd
    float v = wsum_acc;
    v += __shfl_xor(v, 16, 64);
    v += __shfl_xor(v, 32, 64);
    float* swsum = (float*)(smem + SWS_OFF);
    if (lane < 16) swsum[wave * 16 + lane] = v;
    __syncthreads();

    const float inv64 = 0.015625f;
#pragma unroll
    for (int bt = 0; bt < 4; ++bt) {
#pragma unroll
        for (int dt = 0; dt < 2; ++dt) {
            const int d = dq * 32 + dt * 16 + l16;
#pragma unroll
            for (int r = 0; r < 4; ++r) {
                const int bl = bt * 16 + quad * 4 + r;
                const int b = b0 + bl;
                const float wsb = swsum[(bt * 2) * 16 + (quad * 4 + r)]
                                + swsum[(bt * 2 + 1) * 16 + (quad * 4 + r)];
                const float xv = x_t[(size_t)b * DD + d];
                const float m = (acc2[bt][dt][r] - 2.f * xv * acc1[bt][dt][r]) * inv64
                              + xv * xv * wsb;
                atomicAdd(&M[(size_t)b * DD + d], m);
            }
        }
    }
}

// ---------------- fallback: fp32, ZERO workspace (safety net)
__global__ __launch_bounds__(256) void hland_fb(const float* __restrict__ x_t,
                                                const float* __restrict__ ref,
                                                float* __restrict__ M) {
    __shared__ float xs[8][257];
    __shared__ float rt[32][257];
    __shared__ float Sv[8][32];
    __shared__ float wv[8][32];
    __shared__ float rsq_s[32];
    __shared__ float xsq_s[8];
    const int t = threadIdx.x;
    const int b0 = blockIdx.x * 8;
    if (t < 8) xsq_s[t] = 0.f;
    __syncthreads();
    {
        const int r = t >> 5, c = (t & 31) * 8;
        const float4 a = *(const float4*)(x_t + (size_t)(b0 + r) * DD + c);
        const float4 b = *(const float4*)(x_t + (size_t)(b0 + r) * DD + c + 4);
        xs[r][c + 0] = a.x; xs[r][c + 1] = a.y; xs[r][c + 2] = a.z; xs[r][c + 3] = a.w;
        xs[r][c + 4] = b.x; xs[r][c + 5] = b.y; xs[r][c + 6] = b.z; xs[r][c + 7] = b.w;
        atomicAdd(&xsq_s[r], a.x*a.x+a.y*a.y+a.z*a.z+a.w*a.w + b.x*b.x+b.y*b.y+b.z*b.z+b.w*b.w);
    }
    __syncthreads();
    float acc2[8], acc1[8], wsum[8];
#pragma unroll
    for (int b = 0; b < 8; ++b) { acc2[b] = 0.f; acc1[b] = 0.f; wsum[b] = 0.f; }
    const int sr = t >> 3, sg = t & 7;
    for (int tile = 0; tile < NN / 32; ++tile) {
        const int n0 = tile * 32;
        Sv[t >> 5][t & 31] = 0.f;
        if (t < 32) rsq_s[t] = 0.f;
        __syncthreads();
        {
            float p = 0.f;
#pragma unroll
            for (int j = 0; j < 8; ++j) {
                const int c = sg * 32 + j * 4;
                const float4 v = *(const float4*)(ref + (size_t)(n0 + sr) * DD + c);
                rt[sr][c + 0] = v.x; rt[sr][c + 1] = v.y; rt[sr][c + 2] = v.z; rt[sr][c + 3] = v.w;
                p += v.x * v.x + v.y * v.y + v.z * v.z + v.w * v.w;
            }
            atomicAdd(&rsq_s[sr], p);
        }
        __syncthreads();
        {
            float part[8];
#pragma unroll
            for (int b = 0; b < 8; ++b) part[b] = 0.f;
            for (int jj = 0; jj < 32; ++jj) {
                const int c = sg * 32 + ((jj + sg * 4) & 31);
                const float rv = rt[sr][c];
#pragma unroll
                for (int b = 0; b < 8; ++b) part[b] += xs[b][c] * rv;
            }
#pragma unroll
            for (int b = 0; b < 8; ++b) atomicAdd(&Sv[b][sr], part[b]);
        }
        __syncthreads();
        {
            const int b = t >> 5, n = t & 31;
            const float dist = xsq_s[b] + rsq_s[n] - 2.f * Sv[b][n];
            wv[b][n] = __expf(dist * (-GAMMA_INV_2SQ));
        }
        __syncthreads();
        for (int n = 0; n < 32; ++n) {
            const float rv = rt[n][t];
            const float rv2 = rv * rv;
#pragma unroll
            for (int b = 0; b < 8; ++b) {
                const float w = wv[b][n];
                acc1[b] += w * rv; acc2[b] += w * rv2; wsum[b] += w;
            }
        }
        __syncthreads();
    }
#pragma unroll
    for (int b = 0; b < 8; ++b) {
        const float xv = xs[b][t];
        M[(size_t)(b0 + b) * DD + t] = acc2[b] - 2.f * xv * acc1[b] + xv * xv * wsum[b];
    }
}

// ---------------- finish: out = 1/(W*M + eps)
__global__ __launch_bounds__(256) void finish_k(float* __restrict__ M,
                                                const float* __restrict__ W) {
    const int i = blockIdx.x * blockDim.x + threadIdx.x;
    const float W0 = W[0];
    float4 m = ((const float4*)M)[i];
    float4 o;
    o.x = 1.f / (W0 * m.x + EPS_C);
    o.y = 1.f / (W0 * m.y + EPS_C);
    o.z = 1.f / (W0 * m.z + EPS_C);
    o.w = 1.f / (W0 * m.w + EPS_C);
    ((float4*)M)[i] = o;
}

extern "C" void kernel_launch(void* const* d_in, const int* in_sizes, int n_in,
                              void* d_out, int out_size, void* d_ws, size_t ws_size,
                              hipStream_t stream) {
    const float* x_t = (const float*)d_in[0];
    const float* ref = (const float*)d_in[1];
    const float* W   = (const float*)d_in[2];
    float* out = (float*)d_out;

    // ws carve: sAg 2MB | sTg 2MB | sT2g 2MB | xbf8 2MB | rsq 32KB | xsq 32KB
    const size_t WS_NEED = (size_t)8 * 1024 * 1024 + 65536;
    if (ws_size >= WS_NEED) {
        char* ws = (char*)d_ws;
        unsigned char* sAg  = (unsigned char*)(ws);
        unsigned char* sTg  = (unsigned char*)(ws + (size_t)2 * 1024 * 1024);
        unsigned char* sT2g = (unsigned char*)(ws + (size_t)4 * 1024 * 1024);
        unsigned char* xbf8 = (unsigned char*)(ws + (size_t)6 * 1024 * 1024);
        float* rsq = (float*)(ws + (size_t)8 * 1024 * 1024);
        float* xsq = (float*)(ws + (size_t)8 * 1024 * 1024 + 32768);

        zero_k<<<(BB * DD / 4) / 256, 256, 0, stream>>>((float4*)out);
        prep_ref<<<NN / 32, 256, 0, stream>>>(ref, sAg, sTg, sT2g, rsq);
        prep_x<<<BB / 32, 256, 0, stream>>>(x_t, xbf8, xsq);
        hland_main<<<(BB / 64) * 4, 512, 0, stream>>>(sAg, sTg, sT2g, rsq, xsq, xbf8, x_t, out);
    } else {
        hland_fb<<<BB / 8, 256, 0, stream>>>(x_t, ref, out);
    }
    finish_k<<<(BB * DD / 4) / 256, 256, 0, stream>>>(out, W);
}

// Round 5
// 161.135 us; speedup vs baseline: 2.4088x; 1.1439x over previous
//
#include <hip/hip_runtime.h>
#include <hip/hip_bf16.h>

// Problem constants
#define BB 8192
#define NN 8192
#define DD 256
#define GAMMA_INV_2SQ 0.0078125f   // 1/(2*8^2) = 1/128
#define EPS_C 0.001f

typedef __attribute__((ext_vector_type(4))) float v4f;   // MFMA acc

// ---- fp8 (OCP e4m3) pack: 4 floats -> u32 (byte0=a .. byte3=d)
__device__ __forceinline__ unsigned f2fp8pk4(float a, float b, float c, float d) {
    int v = 0;
    v = __builtin_amdgcn_cvt_pk_fp8_f32(a, b, v, false);
    v = __builtin_amdgcn_cvt_pk_fp8_f32(c, d, v, true);
    return (unsigned)v;
}

// ---- async global->LDS, 16B per lane (lds base wave-uniform)
typedef const __attribute__((address_space(1))) void* gas_t;
typedef __attribute__((address_space(3))) void* las_t;
__device__ __forceinline__ void ld16(const void* g, void* l) {
    __builtin_amdgcn_global_load_lds((gas_t)g, (las_t)l, 16, 0, 0);
}

// ---------------- fused prep (512 blocks x 256):
// blocks [0,256): ref -> swizzled fp8 tile images + rsq
// blocks [256,512): x -> fp8 rows + xsq, and optionally zero M (atomic path)
__global__ __launch_bounds__(256) void prep_all(const float* __restrict__ ref,
                                                const float* __restrict__ x,
                                                unsigned char* __restrict__ sAg,
                                                unsigned char* __restrict__ sTg,
                                                unsigned char* __restrict__ sT2g,
                                                unsigned char* __restrict__ xbf8,
                                                float* __restrict__ rsq,
                                                float* __restrict__ xsq,
                                                float* __restrict__ M,
                                                int zeroM) {
    __shared__ float tile[32][257];
    __shared__ float rs[32];
    const int tid = threadIdx.x;
    if (blockIdx.x < 256) {
        const int n0 = blockIdx.x * 32;
        if (tid < 32) rs[tid] = 0.f;
        __syncthreads();
        const int r = tid >> 3, p8 = tid & 7;
        float partial = 0.f;
#pragma unroll
        for (int j = 0; j < 8; ++j) {
            const int c = p8 * 32 + j * 4;
            const float4 v = *(const float4*)(ref + (size_t)(n0 + r) * DD + c);
            partial += v.x * v.x + v.y * v.y + v.z * v.z + v.w * v.w;
            tile[r][c + 0] = v.x; tile[r][c + 1] = v.y;
            tile[r][c + 2] = v.z; tile[r][c + 3] = v.w;
        }
        atomicAdd(&rs[r], partial);
        __syncthreads();
        if (tid < 32) rsq[n0 + tid] = rs[tid];
        // sAg image: byte[r*256 + cp*8 + j], cp=(c&16)|((c^(r&15))&15)
        {
            unsigned char* dstA = sAg + (size_t)blockIdx.x * 8192 + r * 256;
#pragma unroll
            for (int c4 = 0; c4 < 4; ++c4) {
                const int c = p8 * 4 + c4;
                const float* s = &tile[r][c * 8];
                const unsigned lo = f2fp8pk4(s[0], s[1], s[2], s[3]);
                const unsigned hi = f2fp8pk4(s[4], s[5], s[6], s[7]);
                const int cp = (c & 16) | ((c ^ (r & 15)) & 15);
                *(uint2*)(dstA + cp * 8) = make_uint2(lo, hi);
            }
        }
        // sTg/sT2g: byte[d*32 + cp*8 + j], cp=c^((d>>2)&3); thread owns column d=tid
        {
            const int d = tid;
            uint2 ch1[4], ch2[4];
#pragma unroll
            for (int c = 0; c < 4; ++c) {
                float v[8], v2[8];
#pragma unroll
                for (int j = 0; j < 8; ++j) { v[j] = tile[c * 8 + j][d]; v2[j] = v[j] * v[j]; }
                const int cp = c ^ ((d >> 2) & 3);
                ch1[cp] = make_uint2(f2fp8pk4(v[0], v[1], v[2], v[3]), f2fp8pk4(v[4], v[5], v[6], v[7]));
                ch2[cp] = make_uint2(f2fp8pk4(v2[0], v2[1], v2[2], v2[3]), f2fp8pk4(v2[4], v2[5], v2[6], v2[7]));
            }
            unsigned char* dT  = sTg  + (size_t)blockIdx.x * 8192 + d * 32;
            unsigned char* dT2 = sT2g + (size_t)blockIdx.x * 8192 + d * 32;
            *(uint4*)(dT)       = make_uint4(ch1[0].x, ch1[0].y, ch1[1].x, ch1[1].y);
            *(uint4*)(dT + 16)  = make_uint4(ch1[2].x, ch1[2].y, ch1[3].x, ch1[3].y);
            *(uint4*)(dT2)      = make_uint4(ch2[0].x, ch2[0].y, ch2[1].x, ch2[1].y);
            *(uint4*)(dT2 + 16) = make_uint4(ch2[2].x, ch2[2].y, ch2[3].x, ch2[3].y);
        }
    } else {
        const int blk = blockIdx.x - 256;
        const int b0 = blk * 32;
        if (tid < 32) rs[tid] = 0.f;
        __syncthreads();
        const int r = tid >> 3, p8 = tid & 7;
        float partial = 0.f;
        unsigned pk[8];
#pragma unroll
        for (int j = 0; j < 8; ++j) {
            const int c = p8 * 32 + j * 4;
            const float4 v = *(const float4*)(x + (size_t)(b0 + r) * DD + c);
            partial += v.x * v.x + v.y * v.y + v.z * v.z + v.w * v.w;
            pk[j] = f2fp8pk4(v.x, v.y, v.z, v.w);
        }
        atomicAdd(&rs[r], partial);
        unsigned char* dst = xbf8 + (size_t)(b0 + r) * DD + p8 * 32;
        *(uint4*)(dst)      = make_uint4(pk[0], pk[1], pk[2], pk[3]);
        *(uint4*)(dst + 16) = make_uint4(pk[4], pk[5], pk[6], pk[7]);
        __syncthreads();
        if (tid < 32) xsq[b0 + tid] = rs[tid];
        if (zeroM) {
            float4* mz = (float4*)M + (size_t)blk * 2048;
#pragma unroll
            for (int j = 0; j < 8; ++j)
                mz[j * 256 + tid] = make_float4(0.f, 0.f, 0.f, 0.f);
        }
    }
}

// ---------------- main fused kernel: fp8 MFMA, 1 barrier/iter, async staging
// grid = 512 blocks (XCD-swizzled), 512 threads (8 waves)
// LDS: sA 2x8K | sT 3x8K | sT2 3x8K | sW 2x2K | rsq 8K | wsum 512B
#define SA_OFF   0
#define ST_OFF   16384
#define ST2_OFF  40960
#define SW_OFF   65536
#define SRSQ_OFF 69632
#define SWS_OFF  77824
#define SMEM_SZ  78336

template <bool ATOMIC>
__global__ __launch_bounds__(512, 4) void hland_main(
        const unsigned char* __restrict__ sAg,
        const unsigned char* __restrict__ sTg,
        const unsigned char* __restrict__ sT2g,
        const float* __restrict__ rsq,
        const float* __restrict__ xsq,
        const unsigned char* __restrict__ xbf8,
        const float* __restrict__ x_t,
        float* __restrict__ M) {
    __shared__ __align__(16) char smem[SMEM_SZ];

    const int tid = threadIdx.x;
    const int wave = tid >> 6, lane = tid & 63;
    const int quad = lane >> 4, l16 = lane & 15;
    // XCD swizzle: blocks on XCD j (= blk%8) share n-quarter q=j>>1
    const int q = (blockIdx.x & 7) >> 1;
    const int btile = ((blockIdx.x >> 3) << 1) | (blockIdx.x & 1);
    const int b0 = btile * 64;
    const int tn0 = q * 64;
    const int nt = wave & 1, btA = wave >> 1, dq = wave;

    const float xsq_lane = xsq[b0 + btA * 16 + l16];
    float wsum_acc = 0.f;
    v4f acc2[4][2], acc1[4][2];
#pragma unroll
    for (int i = 0; i < 4; ++i)
#pragma unroll
        for (int j = 0; j < 2; ++j) { acc2[i][j] = (v4f){0,0,0,0}; acc1[i][j] = (v4f){0,0,0,0}; }

    // hoisted loop-invariant x fragments (B operand of Phase B)
    long bfr[8];
    {
        const unsigned char* xb = xbf8 + (size_t)(b0 + btA * 16 + l16) * 256 + quad * 8;
#pragma unroll
        for (int kc = 0; kc < 8; ++kc) bfr[kc] = *(const long*)(xb + kc * 32);
    }

    const int stage_goff = wave * 1024 + lane * 16;
    const int stage_loff = wave * 1024;

    // prologue: stage rsq quarter (8 KB) + tile 0
    ((float4*)(smem + SRSQ_OFF))[tid] = ((const float4*)(rsq + tn0 * 32))[tid];
    {
        const size_t g = (size_t)tn0 * 8192 + stage_goff;
        ld16(sAg + g,  smem + SA_OFF  + stage_loff);
        ld16(sTg + g,  smem + ST_OFF  + stage_loff);
        ld16(sT2g + g, smem + ST2_OFF + stage_loff);
    }
    __syncthreads();

    int sp = 0, tp = 0;
    for (int it = 0; it < 64; ++it) {
        const int spn = sp ^ 1;
        const int tpn = (tp == 2) ? 0 : tp + 1;
        const int tpd = (tp == 0) ? 2 : tp - 1;

        if (it < 63) {
            const size_t g = (size_t)(tn0 + it + 1) * 8192 + stage_goff;
            ld16(sAg + g,  smem + SA_OFF  + spn * 8192 + stage_loff);
            ld16(sTg + g,  smem + ST_OFF  + tpn * 8192 + stage_loff);
            ld16(sT2g + g, smem + ST2_OFF + tpn * 8192 + stage_loff);
        }

        // ---- Phase B(it): S^T[n][b]
        v4f S = (v4f){0,0,0,0};
        {
            const char* saB = smem + SA_OFF + sp * 8192 + (nt * 16 + l16) * 256;
#pragma unroll
            for (int kc = 0; kc < 8; ++kc) {
                const int c = kc * 4 + quad;
                const int cp = (c & 16) | ((c ^ l16) & 15);
                const long a = *(const long*)(saB + cp * 8);
                S = __builtin_amdgcn_mfma_f32_16x16x32_fp8_fp8(a, bfr[kc], S, 0, 0, 0);
            }
        }

        // ---- Phase C(it): w = exp(-dist/128); write 64*w fp8 to sW[sp]
        {
            const float4 r4 = *(const float4*)(smem + SRSQ_OFF + it * 128 + nt * 64 + quad * 16);
            float w4[4];
            w4[0] = __expf((xsq_lane + r4.x - 2.f * S[0]) * (-GAMMA_INV_2SQ));
            w4[1] = __expf((xsq_lane + r4.y - 2.f * S[1]) * (-GAMMA_INV_2SQ));
            w4[2] = __expf((xsq_lane + r4.z - 2.f * S[2]) * (-GAMMA_INV_2SQ));
            w4[3] = __expf((xsq_lane + r4.w - 2.f * S[3]) * (-GAMMA_INV_2SQ));
            wsum_acc += w4[0] + w4[1] + w4[2] + w4[3];
            const unsigned pk = f2fp8pk4(w4[0] * 64.f, w4[1] * 64.f, w4[2] * 64.f, w4[3] * 64.f);
            const int bl = btA * 16 + l16;
            const int c8 = nt * 2 + (quad >> 1);
            *(unsigned*)(smem + SW_OFF + sp * 2048 + bl * 32
                         + (c8 ^ ((bl >> 2) & 3)) * 8 + (quad & 1) * 4) = pk;
        }

        // ---- Phase D(it-1)
        if (it > 0) {
            const char* swb  = smem + SW_OFF  + spn * 2048;
            const char* stb  = smem + ST_OFF  + tpd * 8192;
            const char* st2b = smem + ST2_OFF + tpd * 8192;
            long wf[4];
#pragma unroll
            for (int bt = 0; bt < 4; ++bt) {
                const int bl = bt * 16 + l16;
                wf[bt] = *(const long*)(swb + bl * 32 + (quad ^ ((bl >> 2) & 3)) * 8);
            }
#pragma unroll
            for (int dt = 0; dt < 2; ++dt) {
                const int d = dq * 32 + dt * 16 + l16;
                const int co = (quad ^ ((d >> 2) & 3)) * 8;
                const long bT  = *(const long*)(stb  + d * 32 + co);
                const long bT2 = *(const long*)(st2b + d * 32 + co);
#pragma unroll
                for (int bt = 0; bt < 4; ++bt) {
                    acc2[bt][dt] = __builtin_amdgcn_mfma_f32_16x16x32_fp8_fp8(wf[bt], bT2, acc2[bt][dt], 0, 0, 0);
                    acc1[bt][dt] = __builtin_amdgcn_mfma_f32_16x16x32_fp8_fp8(wf[bt], bT,  acc1[bt][dt], 0, 0, 0);
                }
            }
        }
        __syncthreads();
        sp = spn; tp = tpn;
    }

    // ---- final Phase D(63)
    {
        const int tpd = (tp == 0) ? 2 : tp - 1;
        const int wsl = sp ^ 1;
        const char* swb  = smem + SW_OFF  + wsl * 2048;
        const char* stb  = smem + ST_OFF  + tpd * 8192;
        const char* st2b = smem + ST2_OFF + tpd * 8192;
        long wf[4];
#pragma unroll
        for (int bt = 0; bt < 4; ++bt) {
            const int bl = bt * 16 + l16;
            wf[bt] = *(const long*)(swb + bl * 32 + (quad ^ ((bl >> 2) & 3)) * 8);
        }
#pragma unroll
        for (int dt = 0; dt < 2; ++dt) {
            const int d = dq * 32 + dt * 16 + l16;
            const int co = (quad ^ ((d >> 2) & 3)) * 8;
            const long bT  = *(const long*)(stb  + d * 32 + co);
            const long bT2 = *(const long*)(st2b + d * 32 + co);
#pragma unroll
            for (int bt = 0; bt < 4; ++bt) {
                acc2[bt][dt] = __builtin_amdgcn_mfma_f32_16x16x32_fp8_fp8(wf[bt], bT2, acc2[bt][dt], 0, 0, 0);
                acc1[bt][dt] = __builtin_amdgcn_mfma_f32_16x16x32_fp8_fp8(wf[bt], bT,  acc1[bt][dt], 0, 0, 0);
            }
        }
    }

    // ---- epilogue
    float v = wsum_acc;
    v += __shfl_xor(v, 16, 64);
    v += __shfl_xor(v, 32, 64);
    float* swsum = (float*)(smem + SWS_OFF);
    if (lane < 16) swsum[wave * 16 + lane] = v;
    __syncthreads();

    float* Mq = ATOMIC ? M : (M + (size_t)q * BB * DD);
    const float inv64 = 0.015625f;
#pragma unroll
    for (int bt = 0; bt < 4; ++bt) {
#pragma unroll
        for (int dt = 0; dt < 2; ++dt) {
            const int d = dq * 32 + dt * 16 + l16;
#pragma unroll
            for (int r = 0; r < 4; ++r) {
                const int bl = bt * 16 + quad * 4 + r;
                const int b = b0 + bl;
                const float wsb = swsum[(bt * 2) * 16 + (quad * 4 + r)]
                                + swsum[(bt * 2 + 1) * 16 + (quad * 4 + r)];
                const float xv = x_t[(size_t)b * DD + d];
                const float m = (acc2[bt][dt][r] - 2.f * xv * acc1[bt][dt][r]) * inv64
                              + xv * xv * wsb;
                if (ATOMIC) atomicAdd(&Mq[(size_t)b * DD + d], m);
                else        Mq[(size_t)b * DD + d] = m;
            }
        }
    }
}

// ---------------- finish (atomic path): out = 1/(W*M + eps) in place
__global__ __launch_bounds__(256) void finish_k(float* __restrict__ M,
                                                const float* __restrict__ W) {
    const int i = blockIdx.x * blockDim.x + threadIdx.x;
    const float W0 = W[0];
    float4 m = ((const float4*)M)[i];
    float4 o;
    o.x = 1.f / (W0 * m.x + EPS_C);
    o.y = 1.f / (W0 * m.y + EPS_C);
    o.z = 1.f / (W0 * m.z + EPS_C);
    o.w = 1.f / (W0 * m.w + EPS_C);
    ((float4*)M)[i] = o;
}

// ---------------- finish (partials path): out = 1/(W*(p0+p1+p2+p3) + eps)
__global__ __launch_bounds__(256) void finish_sum(const float4* __restrict__ Mp,
                                                  const float* __restrict__ W,
                                                  float4* __restrict__ out) {
    const size_t i = (size_t)blockIdx.x * blockDim.x + threadIdx.x;
    const size_t stride = (size_t)BB * DD / 4;
    const float W0 = W[0];
    const float4 a = Mp[i], b = Mp[i + stride], c = Mp[i + 2 * stride], d = Mp[i + 3 * stride];
    float4 o;
    o.x = 1.f / (W0 * (a.x + b.x + c.x + d.x) + EPS_C);
    o.y = 1.f / (W0 * (a.y + b.y + c.y + d.y) + EPS_C);
    o.z = 1.f / (W0 * (a.z + b.z + c.z + d.z) + EPS_C);
    o.w = 1.f / (W0 * (a.w + b.w + c.w + d.w) + EPS_C);
    out[i] = o;
}

// ---------------- fallback: fp32, ZERO workspace (safety net)
__global__ __launch_bounds__(256) void hland_fb(const float* __restrict__ x_t,
                                                const float* __restrict__ ref,
                                                float* __restrict__ M) {
    __shared__ float xs[8][257];
    __shared__ float rt[32][257];
    __shared__ float Sv[8][32];
    __shared__ float wv[8][32];
    __shared__ float rsq_s[32];
    __shared__ float xsq_s[8];
    const int t = threadIdx.x;
    const int b0 = blockIdx.x * 8;
    if (t < 8) xsq_s[t] = 0.f;
    __syncthreads();
    {
        const int r = t >> 5, c = (t & 31) * 8;
        const float4 a = *(const float4*)(x_t + (size_t)(b0 + r) * DD + c);
        const float4 b = *(const float4*)(x_t + (size_t)(b0 + r) * DD + c + 4);
        xs[r][c + 0] = a.x; xs[r][c + 1] = a.y; xs[r][c + 2] = a.z; xs[r][c + 3] = a.w;
        xs[r][c + 4] = b.x; xs[r][c + 5] = b.y; xs[r][c + 6] = b.z; xs[r][c + 7] = b.w;
        atomicAdd(&xsq_s[r], a.x*a.x+a.y*a.y+a.z*a.z+a.w*a.w + b.x*b.x+b.y*b.y+b.z*b.z+b.w*b.w);
    }
    __syncthreads();
    float acc2[8], acc1[8], wsum[8];
#pragma unroll
    for (int b = 0; b < 8; ++b) { acc2[b] = 0.f; acc1[b] = 0.f; wsum[b] = 0.f; }
    const int sr = t >> 3, sg = t & 7;
    for (int tile = 0; tile < NN / 32; ++tile) {
        const int n0 = tile * 32;
        Sv[t >> 5][t & 31] = 0.f;
        if (t < 32) rsq_s[t] = 0.f;
        __syncthreads();
        {
            float p = 0.f;
#pragma unroll
            for (int j = 0; j < 8; ++j) {
                const int c = sg * 32 + j * 4;
                const float4 v = *(const float4*)(ref + (size_t)(n0 + sr) * DD + c);
                rt[sr][c + 0] = v.x; rt[sr][c + 1] = v.y; rt[sr][c + 2] = v.z; rt[sr][c + 3] = v.w;
                p += v.x * v.x + v.y * v.y + v.z * v.z + v.w * v.w;
            }
            atomicAdd(&rsq_s[sr], p);
        }
        __syncthreads();
        {
            float part[8];
#pragma unroll
            for (int b = 0; b < 8; ++b) part[b] = 0.f;
            for (int jj = 0; jj < 32; ++jj) {
                const int c = sg * 32 + ((jj + sg * 4) & 31);
                const float rv = rt[sr][c];
#pragma unroll
                for (int b = 0; b < 8; ++b) part[b] += xs[b][c] * rv;
            }
#pragma unroll
            for (int b = 0; b < 8; ++b) atomicAdd(&Sv[b][sr], part[b]);
        }
        __syncthreads();
        {
            const int b = t >> 5, n = t & 31;
            const float dist = xsq_s[b] + rsq_s[n] - 2.f * Sv[b][n];
            wv[b][n] = __expf(dist * (-GAMMA_INV_2SQ));
        }
        __syncthreads();
        for (int n = 0; n < 32; ++n) {
            const float rv = rt[n][t];
            const float rv2 = rv * rv;
#pragma unroll
            for (int b = 0; b < 8; ++b) {
                const float w = wv[b][n];
                acc1[b] += w * rv; acc2[b] += w * rv2; wsum[b] += w;
            }
        }
        __syncthreads();
    }
#pragma unroll
    for (int b = 0; b < 8; ++b) {
        const float xv = xs[b][t];
        M[(size_t)(b0 + b) * DD + t] = acc2[b] - 2.f * xv * acc1[b] + xv * xv * wsum[b];
    }
}

extern "C" void kernel_launch(void* const* d_in, const int* in_sizes, int n_in,
                              void* d_out, int out_size, void* d_ws, size_t ws_size,
                              hipStream_t stream) {
    const float* x_t = (const float*)d_in[0];
    const float* ref = (const float*)d_in[1];
    const float* W   = (const float*)d_in[2];
    float* out = (float*)d_out;

    const size_t PART_SZ = (size_t)BB * DD * 4;                  // 8 MB per partial
    const size_t TILES_SZ = (size_t)8 * 1024 * 1024 + 65536;     // images + rsq/xsq
    const size_t WS_A = 4 * PART_SZ + TILES_SZ;                  // ~40.06 MB
    const size_t WS_B = TILES_SZ;                                // ~8.06 MB

    if (ws_size >= WS_B) {
        const bool partials = (ws_size >= WS_A);
        char* ws = (char*)d_ws;
        float* Mp = (float*)ws;                                  // 4 partials (path A)
        char* tb = partials ? (ws + 4 * PART_SZ) : ws;
        unsigned char* sAg  = (unsigned char*)(tb);
        unsigned char* sTg  = (unsigned char*)(tb + (size_t)2 * 1024 * 1024);
        unsigned char* sT2g = (unsigned char*)(tb + (size_t)4 * 1024 * 1024);
        unsigned char* xbf8 = (unsigned char*)(tb + (size_t)6 * 1024 * 1024);
        float* rsq = (float*)(tb + (size_t)8 * 1024 * 1024);
        float* xsq = (float*)(tb + (size_t)8 * 1024 * 1024 + 32768);

        prep_all<<<512, 256, 0, stream>>>(ref, x_t, sAg, sTg, sT2g, xbf8, rsq, xsq,
                                          out, partials ? 0 : 1);
        if (partials) {
            hland_main<false><<<512, 512, 0, stream>>>(sAg, sTg, sT2g, rsq, xsq, xbf8, x_t, Mp);
            finish_sum<<<(BB * DD / 4) / 256, 256, 0, stream>>>((const float4*)Mp, W, (float4*)out);
        } else {
            hland_main<true><<<512, 512, 0, stream>>>(sAg, sTg, sT2g, rsq, xsq, xbf8, x_t, out);
            finish_k<<<(BB * DD / 4) / 256, 256, 0, stream>>>(out, W);
        }
    } else {
        hland_fb<<<BB / 8, 256, 0, stream>>>(x_t, ref, out);
        finish_k<<<(BB * DD / 4) / 256, 256, 0, stream>>>(out, W);
    }
}